// Round 4
// baseline (3774.826 us; speedup 1.0000x reference)
//
#include <hip/hip_runtime.h>
#include <math.h>

typedef __attribute__((ext_vector_type(8))) short short8;
typedef __attribute__((ext_vector_type(4))) float f32x4;

#define N_NODES 50000
#define NUM_REL 8
#define IN_DIM 128
#define HID 256
#define E_EDGES 1600000
#define M_DEC 200000
#define K1 (IN_DIM + NUM_REL*IN_DIM)   /* 1152 */
#define K2 (HID + NUM_REL*HID)         /* 2304 */
#define LN_EPS 1e-5f
#define CHUNK 4096                     /* nodes per conv chunk */
#define NCHUNK 13                      /* ceil(50000/4096) */

__device__ __forceinline__ float b2f(ushort u) {
    union { unsigned int i; float f; } v; v.i = ((unsigned int)u) << 16; return v.f;
}
__device__ __forceinline__ ushort f2b(float f) {
    union { float f; unsigned int i; } v; v.f = f;
    unsigned int r = v.i + 0x7FFFu + ((v.i >> 16) & 1u);
    return (ushort)(r >> 16);
}
__device__ __forceinline__ float gelu_exact(float x) {
    return 0.5f * x * (1.0f + erff(x * 0.70710678118654752f));
}

// ---------------- CSR build ----------------
__global__ void count_kernel(const int* __restrict__ ei, int* __restrict__ cnt) {
    int e = blockIdx.x * 256 + threadIdx.x;
    if (e < E_EDGES) atomicAdd(&cnt[ei[E_EDGES + e]], 1);
}

__global__ void scan_kernel(const int* __restrict__ cnt, int* __restrict__ row_ptr, int n) {
    __shared__ int tsum[1024];
    const int t = threadIdx.x;
    const int CH = (n + 1023) / 1024;   // 49
    const int base = t * CH;
    int s = 0;
    for (int i = 0; i < CH; ++i) { int idx = base + i; if (idx < n) s += cnt[idx]; }
    tsum[t] = s;
    __syncthreads();
    for (int off = 1; off < 1024; off <<= 1) {
        int v = (t >= off) ? tsum[t - off] : 0;
        __syncthreads();
        tsum[t] += v;
        __syncthreads();
    }
    int run = tsum[t] - s;   // exclusive prefix
    for (int i = 0; i < CH; ++i) {
        int idx = base + i;
        if (idx < n) { row_ptr[idx] = run; run += cnt[idx]; }
    }
    if (t == 1023) row_ptr[n] = tsum[1023];
}

__global__ void fill_kernel(const int* __restrict__ ei, const int* __restrict__ et,
                            const int* __restrict__ row_ptr, int* __restrict__ cursor,
                            unsigned int* __restrict__ epk) {
    int e = blockIdx.x * 256 + threadIdx.x;
    if (e >= E_EDGES) return;
    int src = ei[e];
    int dst = ei[E_EDGES + e];
    int r   = et[e];
    int pos = row_ptr[dst] + atomicAdd(&cursor[dst], 1);
    if (pos >= 0 && pos < E_EDGES)
        epk[pos] = (unsigned int)src | ((unsigned int)r << 16);   // src < 65536
}

// ---------------- weight packing: fp32 sources -> bf16 transposed Bt[n][k] ----------------
__global__ void pack_enc(const float* __restrict__ root1, const float* __restrict__ W1,
                         const float* __restrict__ root2, const float* __restrict__ W2,
                         ushort* __restrict__ B1t, ushort* __restrict__ B2t) {
    int idx = blockIdx.x * 256 + threadIdx.x;
    const int n1 = HID * K1;            // 294912
    if (idx < n1) {
        int n = idx / K1, k = idx % K1;
        float v;
        if (k < IN_DIM) v = root1[k * HID + n];
        else { int kk = k - IN_DIM; v = W1[(size_t)(kk >> 7) * IN_DIM * HID + (kk & 127) * HID + n]; }
        B1t[(size_t)n * K1 + k] = f2b(v);
    } else {
        int j = idx - n1;
        if (j >= HID * K2) return;
        int n = j / K2, k = j % K2;
        float v;
        if (k < HID) v = root2[k * HID + n];
        else { int kk = k - HID; v = W2[(size_t)(kk >> 8) * HID * HID + (kk & 255) * HID + n]; }
        B2t[(size_t)n * K2 + k] = f2b(v);
    }
}

__global__ void pack_mlp(const float* __restrict__ mw1, const float* __restrict__ mw2,
                         ushort* __restrict__ w1t, ushort* __restrict__ w2t) {
    int idx = blockIdx.x * 256 + threadIdx.x;
    const int n1 = 256 * 512;           // w1t [256][512]
    if (idx < n1) {
        int n = idx / 512, k = idx % 512;
        w1t[n * 512 + k] = f2b(mw1[k * 256 + n]);
    } else {
        int j = idx - n1;
        if (j >= 128 * 256) return;
        int n = j / 256, k = j % 256;
        w2t[n * 256 + k] = f2b(mw2[k * 128 + n]);
    }
}

// ---------------- aggregation (fp32 gather, normalized bf16 out, chunked) ----------------
__global__ void agg1_kernel(const float* __restrict__ x, const int* __restrict__ row_ptr,
                            const unsigned int* __restrict__ epk, ushort* __restrict__ Achunk,
                            int n0) {
    __shared__ float acc[NUM_REL * IN_DIM];
    __shared__ int cnt[NUM_REL];
    const int n = n0 + blockIdx.x, t = threadIdx.x;   // 128 threads
    if (n >= N_NODES) return;
    for (int i = t; i < NUM_REL * IN_DIM; i += 128) acc[i] = 0.f;
    if (t < NUM_REL) cnt[t] = 0;
    __syncthreads();
    int beg = row_ptr[n], end = row_ptr[n + 1];
    if (beg < 0) beg = 0;
    if (end > E_EDGES) end = E_EDGES;
    for (int e = beg; e < end; ++e) {
        unsigned int p = epk[e];
        int src = (int)(p & 0xFFFFu);
        int r = (int)((p >> 16) & 7u);
        if (src >= N_NODES) src = N_NODES - 1;
        acc[r * IN_DIM + t] += x[(size_t)src * IN_DIM + t];
        if (t == 0) cnt[r]++;
    }
    __syncthreads();
    ushort* Arow = Achunk + (size_t)blockIdx.x * K1;
    Arow[t] = f2b(x[(size_t)n * IN_DIM + t]);
#pragma unroll
    for (int r = 0; r < NUM_REL; ++r) {
        float c = (float)cnt[r];
        float inv = c > 0.f ? 1.f / c : 0.f;
        Arow[IN_DIM + r * IN_DIM + t] = f2b(acc[r * IN_DIM + t] * inv);
    }
}

__global__ void agg2_kernel(const ushort* __restrict__ h1, const int* __restrict__ row_ptr,
                            const unsigned int* __restrict__ epk, ushort* __restrict__ Achunk,
                            int n0) {
    __shared__ float acc[NUM_REL * HID];
    __shared__ int cnt[NUM_REL];
    const int n = n0 + blockIdx.x, t = threadIdx.x;   // 256 threads
    if (n >= N_NODES) return;
    for (int i = t; i < NUM_REL * HID; i += 256) acc[i] = 0.f;
    if (t < NUM_REL) cnt[t] = 0;
    __syncthreads();
    int beg = row_ptr[n], end = row_ptr[n + 1];
    if (beg < 0) beg = 0;
    if (end > E_EDGES) end = E_EDGES;
    for (int e = beg; e < end; ++e) {
        unsigned int p = epk[e];
        int src = (int)(p & 0xFFFFu);
        int r = (int)((p >> 16) & 7u);
        if (src >= N_NODES) src = N_NODES - 1;
        acc[r * HID + t] += b2f(h1[(size_t)src * HID + t]);
        if (t == 0) cnt[r]++;
    }
    __syncthreads();
    ushort* Arow = Achunk + (size_t)blockIdx.x * K2;
    Arow[t] = h1[(size_t)n * HID + t];
#pragma unroll
    for (int r = 0; r < NUM_REL; ++r) {
        float c = (float)cnt[r];
        float inv = c > 0.f ? 1.f / c : 0.f;
        Arow[HID + r * HID + t] = f2b(acc[r * HID + t] * inv);
    }
}

// ---------------- GEMM: C[M,256] = A[M,K] @ Bt[256,K]^T, bf16 in, fp32 out ----------------
__global__ __launch_bounds__(256) void gemm_bt(const ushort* __restrict__ A,
                                               const ushort* __restrict__ Bt,
                                               float* __restrict__ C,
                                               int M, int N, int K) {
    __shared__ __align__(16) ushort As[128][72];
    __shared__ __align__(16) ushort Bs[128][72];
    const int tid = threadIdx.x;
    const int wave = tid >> 6, lane = tid & 63;
    const int wm = (wave & 1) * 64, wn = (wave >> 1) * 64;
    const int row0 = blockIdx.x * 128, col0 = blockIdx.y * 128;
    const int lm = lane & 15, lk = (lane >> 4) * 8;
    f32x4 acc[4][4];
#pragma unroll
    for (int i = 0; i < 4; ++i)
#pragma unroll
        for (int j = 0; j < 4; ++j) acc[i][j] = (f32x4){0.f, 0.f, 0.f, 0.f};

    for (int k0 = 0; k0 < K; k0 += 64) {
#pragma unroll
        for (int i = 0; i < 4; ++i) {
            int c = tid + i * 256;
            int r = c >> 3, kc = (c & 7) * 8;
            uint4 va = make_uint4(0u, 0u, 0u, 0u);
            int gr = row0 + r;
            if (gr < M) va = *(const uint4*)(A + (size_t)gr * K + k0 + kc);
            *(uint4*)&As[r][kc] = va;
            uint4 vb = make_uint4(0u, 0u, 0u, 0u);
            int gn = col0 + r;
            if (gn < N) vb = *(const uint4*)(Bt + (size_t)gn * K + k0 + kc);
            *(uint4*)&Bs[r][kc] = vb;
        }
        __syncthreads();
#pragma unroll
        for (int kk = 0; kk < 2; ++kk) {
            short8 af[4], bfv[4];
#pragma unroll
            for (int i = 0; i < 4; ++i) af[i] = *(const short8*)&As[wm + i * 16 + lm][kk * 32 + lk];
#pragma unroll
            for (int j = 0; j < 4; ++j) bfv[j] = *(const short8*)&Bs[wn + j * 16 + lm][kk * 32 + lk];
#pragma unroll
            for (int i = 0; i < 4; ++i)
#pragma unroll
                for (int j = 0; j < 4; ++j)
                    acc[i][j] = __builtin_amdgcn_mfma_f32_16x16x32_bf16(af[i], bfv[j], acc[i][j], 0, 0, 0);
        }
        __syncthreads();
    }
    const int rr = (lane >> 4) * 4, cc = lane & 15;
#pragma unroll
    for (int i = 0; i < 4; ++i)
#pragma unroll
        for (int r = 0; r < 4; ++r) {
            int row = row0 + wm + i * 16 + rr + r;
            if (row >= M) continue;
#pragma unroll
            for (int j = 0; j < 4; ++j) {
                int col = col0 + wn + j * 16 + cc;
                C[(size_t)row * N + col] = acc[i][j][r];
            }
        }
}

// ---------------- bias + relu + LayerNorm (+optional residual add), chunked ----------------
__global__ void ln_kernel(const float* __restrict__ raw, const float* __restrict__ bias,
                          const float* __restrict__ g, const float* __restrict__ b,
                          const ushort* __restrict__ addsrc, ushort* __restrict__ outp,
                          int n0, int count) {
    const int wave = threadIdx.x >> 6, lane = threadIdx.x & 63;
    const int row = blockIdx.x * 4 + wave;          // chunk-local row
    if (row >= count) return;
    const int grow = n0 + row;                       // global node row
    const float* rp = raw + (size_t)row * HID;
    float4 v = *(const float4*)(rp + lane * 4);
    float h0 = fmaxf(v.x + bias[lane * 4 + 0], 0.f);
    float h1 = fmaxf(v.y + bias[lane * 4 + 1], 0.f);
    float h2 = fmaxf(v.z + bias[lane * 4 + 2], 0.f);
    float h3 = fmaxf(v.w + bias[lane * 4 + 3], 0.f);
    float s = h0 + h1 + h2 + h3;
#pragma unroll
    for (int off = 32; off >= 1; off >>= 1) s += __shfl_xor(s, off, 64);
    float mu = s * (1.f / HID);
    float d0 = h0 - mu, d1 = h1 - mu, d2 = h2 - mu, d3 = h3 - mu;
    float ss = d0 * d0 + d1 * d1 + d2 * d2 + d3 * d3;
#pragma unroll
    for (int off = 32; off >= 1; off >>= 1) ss += __shfl_xor(ss, off, 64);
    float rs = rsqrtf(ss * (1.f / HID) + LN_EPS);
    float o[4] = {d0 * rs, d1 * rs, d2 * rs, d3 * rs};
    ushort res[4];
#pragma unroll
    for (int k = 0; k < 4; ++k) {
        int c = lane * 4 + k;
        float ov = o[k] * g[c] + b[c];
        if (addsrc) ov += b2f(addsrc[(size_t)grow * HID + c]);
        res[k] = f2b(ov);
    }
    unsigned int packed[2];
    packed[0] = (unsigned int)res[0] | ((unsigned int)res[1] << 16);
    packed[1] = (unsigned int)res[2] | ((unsigned int)res[3] << 16);
    *(uint2*)(outp + (size_t)grow * HID + lane * 4) = make_uint2(packed[0], packed[1]);
}

// ---------------- fused decode MLP (bf16 MFMA, fp32 out) ----------------
__global__ __launch_bounds__(256) void decode_kernel(
    const ushort* __restrict__ hf, const int* __restrict__ dec,
    const ushort* __restrict__ w1t, const float* __restrict__ b1,
    const ushort* __restrict__ w2t, const float* __restrict__ b2,
    const float* __restrict__ w3, const float* __restrict__ b3,
    float* __restrict__ outp, int M) {
    __shared__ __align__(16) ushort Zs[32][520];
    __shared__ __align__(16) ushort z1s[32][264];
    __shared__ __align__(16) ushort z2s[32][136];
    const int tid = threadIdx.x;
    const int wave = tid >> 6, lane = tid & 63;
    const int lm = lane & 15, lk = (lane >> 4) * 8, rr = (lane >> 4) * 4;
    const int e0 = blockIdx.x * 32;

    // stage Z = [h[a] | h[b]] : 32 rows x 512 (bf16)
#pragma unroll
    for (int j = 0; j < 8; ++j) {
        int c = tid + j * 256;
        int row = c >> 6, cc = c & 63;
        int node = dec[(size_t)(e0 + row) * 2 + (cc >> 5)];
        if (node < 0) node = 0;
        if (node >= N_NODES) node = N_NODES - 1;
        *(uint4*)&Zs[row][cc * 8] = *(const uint4*)(hf + (size_t)node * HID + (cc & 31) * 8);
    }
    __syncthreads();

    // L1: [32,512] @ w1t[256][512]^T -> gelu -> z1s [32,256]
    f32x4 acc1[2][4];
#pragma unroll
    for (int i = 0; i < 2; ++i)
#pragma unroll
        for (int j = 0; j < 4; ++j) acc1[i][j] = (f32x4){0.f, 0.f, 0.f, 0.f};
    const int n0 = wave * 64;
    for (int ks = 0; ks < 16; ++ks) {
        short8 af[2], bfv[4];
#pragma unroll
        for (int i = 0; i < 2; ++i) af[i] = *(const short8*)&Zs[i * 16 + lm][ks * 32 + lk];
#pragma unroll
        for (int j = 0; j < 4; ++j) {
            int n = n0 + j * 16 + lm;
            bfv[j] = *(const short8*)(w1t + (size_t)n * 512 + ks * 32 + lk);
        }
#pragma unroll
        for (int i = 0; i < 2; ++i)
#pragma unroll
            for (int j = 0; j < 4; ++j)
                acc1[i][j] = __builtin_amdgcn_mfma_f32_16x16x32_bf16(af[i], bfv[j], acc1[i][j], 0, 0, 0);
    }
#pragma unroll
    for (int i = 0; i < 2; ++i)
#pragma unroll
        for (int j = 0; j < 4; ++j)
#pragma unroll
            for (int r = 0; r < 4; ++r) {
                int m = i * 16 + rr + r;
                int n = n0 + j * 16 + lm;
                float v = acc1[i][j][r] + b1[n];
                z1s[m][n] = f2b(gelu_exact(v));
            }
    __syncthreads();

    // L2: [32,256] @ w2t[128][256]^T -> gelu -> z2s [32,128]
    f32x4 acc2[2][2];
#pragma unroll
    for (int i = 0; i < 2; ++i)
#pragma unroll
        for (int j = 0; j < 2; ++j) acc2[i][j] = (f32x4){0.f, 0.f, 0.f, 0.f};
    const int n0b = wave * 32;
    for (int ks = 0; ks < 8; ++ks) {
        short8 af[2], bfv[2];
#pragma unroll
        for (int i = 0; i < 2; ++i) af[i] = *(const short8*)&z1s[i * 16 + lm][ks * 32 + lk];
#pragma unroll
        for (int j = 0; j < 2; ++j) {
            int n = n0b + j * 16 + lm;
            bfv[j] = *(const short8*)(w2t + (size_t)n * 256 + ks * 32 + lk);
        }
#pragma unroll
        for (int i = 0; i < 2; ++i)
#pragma unroll
            for (int j = 0; j < 2; ++j)
                acc2[i][j] = __builtin_amdgcn_mfma_f32_16x16x32_bf16(af[i], bfv[j], acc2[i][j], 0, 0, 0);
    }
#pragma unroll
    for (int i = 0; i < 2; ++i)
#pragma unroll
        for (int j = 0; j < 2; ++j)
#pragma unroll
            for (int r = 0; r < 4; ++r) {
                int m = i * 16 + rr + r;
                int n = n0b + j * 16 + lm;
                float v = acc2[i][j][r] + b2[n];
                z2s[m][n] = f2b(gelu_exact(v));
            }
    __syncthreads();

    // L3: [32,128] @ w3[128,2] + b3 (fp32 out)
    if (wave == 0) {
        int e = lane >> 1, c = lane & 1;
        float s = b3[c];
        for (int k = 0; k < 128; ++k) s += b2f(z2s[e][k]) * w3[k * 2 + c];
        int ge = e0 + e;
        if (ge < M) outp[(size_t)ge * 2 + c] = s;
    }
}

// ---------------- launch ----------------
extern "C" void kernel_launch(void* const* d_in, const int* in_sizes, int n_in,
                              void* d_out, int out_size, void* d_ws, size_t ws_size,
                              hipStream_t stream) {
    const float* x          = (const float*)d_in[0];
    const int*   edge_index = (const int*)d_in[1];
    const int*   edge_type  = (const int*)d_in[2];
    const int*   dec_edges  = (const int*)d_in[3];
    const float* W1         = (const float*)d_in[4];
    const float* root1      = (const float*)d_in[5];
    const float* b1         = (const float*)d_in[6];
    const float* W2         = (const float*)d_in[7];
    const float* root2      = (const float*)d_in[8];
    const float* b2         = (const float*)d_in[9];
    const float* ln1_g      = (const float*)d_in[10];
    const float* ln1_b      = (const float*)d_in[11];
    const float* ln2_g      = (const float*)d_in[12];
    const float* ln2_b      = (const float*)d_in[13];
    const float* mlp_w1     = (const float*)d_in[14];
    const float* mlp_b1     = (const float*)d_in[15];
    const float* mlp_w2     = (const float*)d_in[16];
    const float* mlp_b2     = (const float*)d_in[17];
    const float* mlp_w3     = (const float*)d_in[18];
    const float* mlp_b3     = (const float*)d_in[19];

    char* ws = (char*)d_ws;
    size_t off = 0;
    auto alloc = [&](size_t bytes) {
        void* p = ws + off;
        off += (bytes + 255) & ~(size_t)255;
        return p;
    };
    // total ~83 MB
    ushort*       Achunk  = (ushort*)alloc((size_t)CHUNK * K2 * 2);       // 18.9 MB (shared conv1/conv2)
    ushort*       B1t     = (ushort*)alloc((size_t)HID * K1 * 2);         // 0.59 MB
    ushort*       B2t     = (ushort*)alloc((size_t)HID * K2 * 2);         // 1.18 MB
    ushort*       w1t     = (ushort*)alloc((size_t)256 * 512 * 2);        // 0.26 MB
    ushort*       w2t     = (ushort*)alloc((size_t)128 * 256 * 2);        // 0.07 MB
    ushort*       h1ln    = (ushort*)alloc((size_t)N_NODES * HID * 2);    // 25.6 MB
    ushort*       hfin    = (ushort*)alloc((size_t)N_NODES * HID * 2);    // 25.6 MB
    float*        hrawc   = (float*)alloc((size_t)CHUNK * HID * 4);       // 4.2 MB
    int*          row_ptr = (int*)alloc((size_t)(N_NODES + 1) * 4);
    int*          tmp     = (int*)alloc((size_t)N_NODES * 4);
    unsigned int* epk     = (unsigned int*)alloc((size_t)E_EDGES * 4);    // 6.4 MB
    size_t total_ws = off;

    // defensive: zero-init the entire used workspace
    hipMemsetAsync(d_ws, 0, total_ws, stream);

    // CSR build
    count_kernel<<<E_EDGES / 256, 256, 0, stream>>>(edge_index, tmp);
    scan_kernel<<<1, 1024, 0, stream>>>(tmp, row_ptr, N_NODES);
    hipMemsetAsync(tmp, 0, (size_t)N_NODES * 4, stream);   // reuse as cursor
    fill_kernel<<<E_EDGES / 256, 256, 0, stream>>>(edge_index, edge_type, row_ptr, tmp, epk);

    // weight packs (fp32 -> bf16)
    pack_enc<<<(HID * K1 + HID * K2 + 255) / 256, 256, 0, stream>>>(root1, W1, root2, W2, B1t, B2t);
    pack_mlp<<<(256 * 512 + 128 * 256 + 255) / 256, 256, 0, stream>>>(mlp_w1, mlp_w2, w1t, w2t);

    // conv1 (chunked: agg -> gemm -> ln per 4096-node slab)
    for (int c = 0; c < NCHUNK; ++c) {
        int n0 = c * CHUNK;
        int m = N_NODES - n0; if (m > CHUNK) m = CHUNK;
        agg1_kernel<<<CHUNK, 128, 0, stream>>>(x, row_ptr, epk, Achunk, n0);
        gemm_bt<<<dim3(CHUNK / 128, 2), 256, 0, stream>>>(Achunk, B1t, hrawc, m, HID, K1);
        ln_kernel<<<CHUNK / 4, 256, 0, stream>>>(hrawc, b1, ln1_g, ln1_b, nullptr, h1ln, n0, m);
    }

    // conv2
    for (int c = 0; c < NCHUNK; ++c) {
        int n0 = c * CHUNK;
        int m = N_NODES - n0; if (m > CHUNK) m = CHUNK;
        agg2_kernel<<<CHUNK, 256, 0, stream>>>(h1ln, row_ptr, epk, Achunk, n0);
        gemm_bt<<<dim3(CHUNK / 128, 2), 256, 0, stream>>>(Achunk, B2t, hrawc, m, HID, K2);
        ln_kernel<<<CHUNK / 4, 256, 0, stream>>>(hrawc, b2, ln2_g, ln2_b, h1ln, hfin, n0, m);
    }

    // decode (fp32 out)
    decode_kernel<<<M_DEC / 32, 256, 0, stream>>>(hfin, dec_edges, w1t, mlp_b1, w2t, mlp_b2,
                                                  mlp_w3, mlp_b3, (float*)d_out, M_DEC);
}

// Round 5
// 1821.707 us; speedup vs baseline: 2.0721x; 2.0721x over previous
//
#include <hip/hip_runtime.h>
#include <math.h>

typedef __attribute__((ext_vector_type(8))) short short8;
typedef __attribute__((ext_vector_type(4))) float f32x4;

#define N_NODES 50000
#define NUM_REL 8
#define IN_DIM 128
#define HID 256
#define E_EDGES 1600000
#define M_DEC 200000
#define K1 (IN_DIM + NUM_REL*IN_DIM)   /* 1152 */
#define K2 (HID + NUM_REL*HID)         /* 2304 */
#define LN_EPS 1e-5f
#define CHUNK 8192
#define NCHUNK 7                       /* ceil(50000/8192) */

__device__ __forceinline__ float b2f(ushort u) {
    union { unsigned int i; float f; } v; v.i = ((unsigned int)u) << 16; return v.f;
}
__device__ __forceinline__ ushort f2b(float f) {
    union { float f; unsigned int i; } v; v.f = f;
    unsigned int r = v.i + 0x7FFFu + ((v.i >> 16) & 1u);
    return (ushort)(r >> 16);
}
__device__ __forceinline__ float gelu_exact(float x) {
    return 0.5f * x * (1.0f + erff(x * 0.70710678118654752f));
}

// ---------------- CSR build ----------------
__global__ void count_kernel(const int* __restrict__ ei, int* __restrict__ cnt) {
    int e = blockIdx.x * 256 + threadIdx.x;
    if (e < E_EDGES) atomicAdd(&cnt[ei[E_EDGES + e]], 1);
}

__global__ void scan_kernel(const int* __restrict__ cnt, int* __restrict__ row_ptr, int n) {
    __shared__ int tsum[1024];
    const int t = threadIdx.x;
    const int CH = (n + 1023) / 1024;
    const int base = t * CH;
    int s = 0;
    for (int i = 0; i < CH; ++i) { int idx = base + i; if (idx < n) s += cnt[idx]; }
    tsum[t] = s;
    __syncthreads();
    for (int off = 1; off < 1024; off <<= 1) {
        int v = (t >= off) ? tsum[t - off] : 0;
        __syncthreads();
        tsum[t] += v;
        __syncthreads();
    }
    int run = tsum[t] - s;
    for (int i = 0; i < CH; ++i) {
        int idx = base + i;
        if (idx < n) { row_ptr[idx] = run; run += cnt[idx]; }
    }
    if (t == 1023) row_ptr[n] = tsum[1023];
}

__global__ void fill_kernel(const int* __restrict__ ei, const int* __restrict__ et,
                            const int* __restrict__ row_ptr, int* __restrict__ cursor,
                            unsigned int* __restrict__ epk) {
    int e = blockIdx.x * 256 + threadIdx.x;
    if (e >= E_EDGES) return;
    int src = ei[e];
    int dst = ei[E_EDGES + e];
    int r   = et[e];
    int pos = row_ptr[dst] + atomicAdd(&cursor[dst], 1);
    if (pos >= 0 && pos < E_EDGES)
        epk[pos] = (unsigned int)src | ((unsigned int)r << 16);
}

// ---------------- weight packing: fp32 -> bf16 transposed Bt[n][k] ----------------
__global__ void pack_enc(const float* __restrict__ root1, const float* __restrict__ W1,
                         const float* __restrict__ root2, const float* __restrict__ W2,
                         ushort* __restrict__ B1t, ushort* __restrict__ B2t) {
    int idx = blockIdx.x * 256 + threadIdx.x;
    const int n1 = HID * K1;
    if (idx < n1) {
        int n = idx / K1, k = idx % K1;
        float v;
        if (k < IN_DIM) v = root1[k * HID + n];
        else { int kk = k - IN_DIM; v = W1[(size_t)(kk >> 7) * IN_DIM * HID + (kk & 127) * HID + n]; }
        B1t[(size_t)n * K1 + k] = f2b(v);
    } else {
        int j = idx - n1;
        if (j >= HID * K2) return;
        int n = j / K2, k = j % K2;
        float v;
        if (k < HID) v = root2[k * HID + n];
        else { int kk = k - HID; v = W2[(size_t)(kk >> 8) * HID * HID + (kk & 255) * HID + n]; }
        B2t[(size_t)n * K2 + k] = f2b(v);
    }
}

__global__ void pack_mlp(const float* __restrict__ mw1, const float* __restrict__ mw2,
                         ushort* __restrict__ w1t, ushort* __restrict__ w2t) {
    int idx = blockIdx.x * 256 + threadIdx.x;
    const int n1 = 256 * 512;
    if (idx < n1) {
        int n = idx / 512, k = idx % 512;
        w1t[n * 512 + k] = f2b(mw1[k * 256 + n]);
    } else {
        int j = idx - n1;
        if (j >= 128 * 256) return;
        int n = j / 256, k = j % 256;
        w2t[n * 256 + k] = f2b(mw2[k * 128 + n]);
    }
}

// ---------------- aggregation (4-way edge-unrolled) ----------------
__global__ void agg1_kernel(const float* __restrict__ x, const int* __restrict__ row_ptr,
                            const unsigned int* __restrict__ epk, ushort* __restrict__ Achunk,
                            int n0) {
    __shared__ float acc[NUM_REL * IN_DIM];
    __shared__ int cnt[NUM_REL];
    const int n = n0 + blockIdx.x, t = threadIdx.x;   // 128 threads
    if (n >= N_NODES) return;
    for (int i = t; i < NUM_REL * IN_DIM; i += 128) acc[i] = 0.f;
    if (t < NUM_REL) cnt[t] = 0;
    __syncthreads();
    int beg = row_ptr[n], end = row_ptr[n + 1];
    if (beg < 0) beg = 0;
    if (end > E_EDGES) end = E_EDGES;
    int e = beg;
    for (; e + 3 < end; e += 4) {
        unsigned int p0 = epk[e], p1 = epk[e+1], p2 = epk[e+2], p3 = epk[e+3];
        float f0 = x[(size_t)(p0 & 0xFFFFu) * IN_DIM + t];
        float f1 = x[(size_t)(p1 & 0xFFFFu) * IN_DIM + t];
        float f2 = x[(size_t)(p2 & 0xFFFFu) * IN_DIM + t];
        float f3 = x[(size_t)(p3 & 0xFFFFu) * IN_DIM + t];
        acc[((p0 >> 16) & 7u) * IN_DIM + t] += f0;
        acc[((p1 >> 16) & 7u) * IN_DIM + t] += f1;
        acc[((p2 >> 16) & 7u) * IN_DIM + t] += f2;
        acc[((p3 >> 16) & 7u) * IN_DIM + t] += f3;
        if (t == 0) { cnt[(p0>>16)&7u]++; cnt[(p1>>16)&7u]++; cnt[(p2>>16)&7u]++; cnt[(p3>>16)&7u]++; }
    }
    for (; e < end; ++e) {
        unsigned int p = epk[e];
        acc[((p >> 16) & 7u) * IN_DIM + t] += x[(size_t)(p & 0xFFFFu) * IN_DIM + t];
        if (t == 0) cnt[(p>>16)&7u]++;
    }
    __syncthreads();
    ushort* Arow = Achunk + (size_t)blockIdx.x * K1;
    Arow[t] = f2b(x[(size_t)n * IN_DIM + t]);
#pragma unroll
    for (int r = 0; r < NUM_REL; ++r) {
        float c = (float)cnt[r];
        float inv = c > 0.f ? 1.f / c : 0.f;
        Arow[IN_DIM + r * IN_DIM + t] = f2b(acc[r * IN_DIM + t] * inv);
    }
}

__global__ void agg2_kernel(const ushort* __restrict__ h1, const int* __restrict__ row_ptr,
                            const unsigned int* __restrict__ epk, ushort* __restrict__ Achunk,
                            int n0) {
    __shared__ float acc[NUM_REL * HID];
    __shared__ int cnt[NUM_REL];
    const int n = n0 + blockIdx.x, t = threadIdx.x;   // 256 threads
    if (n >= N_NODES) return;
    for (int i = t; i < NUM_REL * HID; i += 256) acc[i] = 0.f;
    if (t < NUM_REL) cnt[t] = 0;
    __syncthreads();
    int beg = row_ptr[n], end = row_ptr[n + 1];
    if (beg < 0) beg = 0;
    if (end > E_EDGES) end = E_EDGES;
    int e = beg;
    for (; e + 3 < end; e += 4) {
        unsigned int p0 = epk[e], p1 = epk[e+1], p2 = epk[e+2], p3 = epk[e+3];
        float f0 = b2f(h1[(size_t)(p0 & 0xFFFFu) * HID + t]);
        float f1 = b2f(h1[(size_t)(p1 & 0xFFFFu) * HID + t]);
        float f2 = b2f(h1[(size_t)(p2 & 0xFFFFu) * HID + t]);
        float f3 = b2f(h1[(size_t)(p3 & 0xFFFFu) * HID + t]);
        acc[((p0 >> 16) & 7u) * HID + t] += f0;
        acc[((p1 >> 16) & 7u) * HID + t] += f1;
        acc[((p2 >> 16) & 7u) * HID + t] += f2;
        acc[((p3 >> 16) & 7u) * HID + t] += f3;
        if (t == 0) { cnt[(p0>>16)&7u]++; cnt[(p1>>16)&7u]++; cnt[(p2>>16)&7u]++; cnt[(p3>>16)&7u]++; }
    }
    for (; e < end; ++e) {
        unsigned int p = epk[e];
        acc[((p >> 16) & 7u) * HID + t] += b2f(h1[(size_t)(p & 0xFFFFu) * HID + t]);
        if (t == 0) cnt[(p>>16)&7u]++;
    }
    __syncthreads();
    ushort* Arow = Achunk + (size_t)blockIdx.x * K2;
    Arow[t] = h1[(size_t)n * HID + t];
#pragma unroll
    for (int r = 0; r < NUM_REL; ++r) {
        float c = (float)cnt[r];
        float inv = c > 0.f ? 1.f / c : 0.f;
        Arow[HID + r * HID + t] = f2b(acc[r * HID + t] * inv);
    }
}

// ---------------- GEMM 64x64 tile: C[M,256] = A[M,K] @ Bt[256,K]^T ----------------
// 4 waves in 2x2; each wave 32x32 via 2x2 MFMA 16x16x32. 18.4KB LDS -> high occupancy.
__global__ __launch_bounds__(256) void gemm64(const ushort* __restrict__ A,
                                              const ushort* __restrict__ Bt,
                                              float* __restrict__ C,
                                              int M, int N, int K) {
    __shared__ __align__(16) ushort As[64][72];
    __shared__ __align__(16) ushort Bs[64][72];
    const int tid = threadIdx.x;
    const int wave = tid >> 6, lane = tid & 63;
    const int wm = (wave & 1) * 32, wn = (wave >> 1) * 32;
    const int row0 = blockIdx.x * 64, col0 = blockIdx.y * 64;
    const int lm = lane & 15, lk = (lane >> 4) * 8;
    f32x4 acc[2][2];
#pragma unroll
    for (int i = 0; i < 2; ++i)
#pragma unroll
        for (int j = 0; j < 2; ++j) acc[i][j] = (f32x4){0.f, 0.f, 0.f, 0.f};

    for (int k0 = 0; k0 < K; k0 += 64) {
#pragma unroll
        for (int i = 0; i < 2; ++i) {
            int c = tid + i * 256;
            int r = c >> 3, kc = (c & 7) * 8;
            uint4 va = make_uint4(0u, 0u, 0u, 0u);
            int gr = row0 + r;
            if (gr < M) va = *(const uint4*)(A + (size_t)gr * K + k0 + kc);
            *(uint4*)&As[r][kc] = va;
            uint4 vb = make_uint4(0u, 0u, 0u, 0u);
            int gn = col0 + r;
            if (gn < N) vb = *(const uint4*)(Bt + (size_t)gn * K + k0 + kc);
            *(uint4*)&Bs[r][kc] = vb;
        }
        __syncthreads();
#pragma unroll
        for (int kk = 0; kk < 2; ++kk) {
            short8 af[2], bfv[2];
#pragma unroll
            for (int i = 0; i < 2; ++i) af[i] = *(const short8*)&As[wm + i * 16 + lm][kk * 32 + lk];
#pragma unroll
            for (int j = 0; j < 2; ++j) bfv[j] = *(const short8*)&Bs[wn + j * 16 + lm][kk * 32 + lk];
#pragma unroll
            for (int i = 0; i < 2; ++i)
#pragma unroll
                for (int j = 0; j < 2; ++j)
                    acc[i][j] = __builtin_amdgcn_mfma_f32_16x16x32_bf16(af[i], bfv[j], acc[i][j], 0, 0, 0);
        }
        __syncthreads();
    }
    const int rr = (lane >> 4) * 4, cc = lane & 15;
#pragma unroll
    for (int i = 0; i < 2; ++i)
#pragma unroll
        for (int r = 0; r < 4; ++r) {
            int row = row0 + wm + i * 16 + rr + r;
            if (row >= M) continue;
#pragma unroll
            for (int j = 0; j < 2; ++j) {
                int col = col0 + wn + j * 16 + cc;
                C[(size_t)row * N + col] = acc[i][j][r];
            }
        }
}

// ---------------- bias + relu + LayerNorm (+optional residual), chunked ----------------
__global__ void ln_kernel(const float* __restrict__ raw, const float* __restrict__ bias,
                          const float* __restrict__ g, const float* __restrict__ b,
                          const ushort* __restrict__ addsrc, ushort* __restrict__ outp,
                          int n0, int count) {
    const int wave = threadIdx.x >> 6, lane = threadIdx.x & 63;
    const int row = blockIdx.x * 4 + wave;
    if (row >= count) return;
    const int grow = n0 + row;
    const float* rp = raw + (size_t)row * HID;
    float4 v = *(const float4*)(rp + lane * 4);
    float h0 = fmaxf(v.x + bias[lane * 4 + 0], 0.f);
    float h1 = fmaxf(v.y + bias[lane * 4 + 1], 0.f);
    float h2 = fmaxf(v.z + bias[lane * 4 + 2], 0.f);
    float h3 = fmaxf(v.w + bias[lane * 4 + 3], 0.f);
    float s = h0 + h1 + h2 + h3;
#pragma unroll
    for (int off = 32; off >= 1; off >>= 1) s += __shfl_xor(s, off, 64);
    float mu = s * (1.f / HID);
    float d0 = h0 - mu, d1 = h1 - mu, d2 = h2 - mu, d3 = h3 - mu;
    float ss = d0 * d0 + d1 * d1 + d2 * d2 + d3 * d3;
#pragma unroll
    for (int off = 32; off >= 1; off >>= 1) ss += __shfl_xor(ss, off, 64);
    float rs = rsqrtf(ss * (1.f / HID) + LN_EPS);
    float o[4] = {d0 * rs, d1 * rs, d2 * rs, d3 * rs};
    ushort res[4];
#pragma unroll
    for (int k = 0; k < 4; ++k) {
        int c = lane * 4 + k;
        float ov = o[k] * g[c] + b[c];
        if (addsrc) ov += b2f(addsrc[(size_t)grow * HID + c]);
        res[k] = f2b(ov);
    }
    unsigned int packed[2];
    packed[0] = (unsigned int)res[0] | ((unsigned int)res[1] << 16);
    packed[1] = (unsigned int)res[2] | ((unsigned int)res[3] << 16);
    *(uint2*)(outp + (size_t)grow * HID + lane * 4) = make_uint2(packed[0], packed[1]);
}

// ---------------- fused decode MLP: direct-global A-fragments, no Z staging ----------------
__global__ __launch_bounds__(256) void decode_kernel(
    const ushort* __restrict__ hf, const int* __restrict__ dec,
    const ushort* __restrict__ w1t, const float* __restrict__ b1,
    const ushort* __restrict__ w2t, const float* __restrict__ b2,
    const float* __restrict__ w3, const float* __restrict__ b3,
    float* __restrict__ outp, int M) {
    __shared__ __align__(16) ushort z1s[32][264];
    __shared__ __align__(16) ushort z2s[32][136];
    const int tid = threadIdx.x;
    const int wave = tid >> 6, lane = tid & 63;
    const int lm = lane & 15, lk = (lane >> 4) * 8, rr = (lane >> 4) * 4;
    const int e0 = blockIdx.x * 32;

    // per-lane node-row base pointers for A-fragment rows lm and lm+16
    const ushort* pa[2];
    const ushort* pb[2];
#pragma unroll
    for (int i = 0; i < 2; ++i) {
        int row = e0 + i * 16 + lm;
        int na = dec[(size_t)row * 2];
        int nb = dec[(size_t)row * 2 + 1];
        if (na < 0) na = 0; if (na >= N_NODES) na = N_NODES - 1;
        if (nb < 0) nb = 0; if (nb >= N_NODES) nb = N_NODES - 1;
        pa[i] = hf + (size_t)na * HID;
        pb[i] = hf + (size_t)nb * HID;
    }

    // L1: [32,512] @ w1t[256][512]^T -> gelu -> z1s [32,256]
    f32x4 acc1[2][4];
#pragma unroll
    for (int i = 0; i < 2; ++i)
#pragma unroll
        for (int j = 0; j < 4; ++j) acc1[i][j] = (f32x4){0.f, 0.f, 0.f, 0.f};
    const int n0 = wave * 64;
#pragma unroll
    for (int ks = 0; ks < 16; ++ks) {
        const int col = ks * 32 + lk;           // 0..511
        short8 af[2], bfv[4];
#pragma unroll
        for (int i = 0; i < 2; ++i)
            af[i] = *(const short8*)((ks < 8 ? pa[i] : pb[i]) + (col & 255));
#pragma unroll
        for (int j = 0; j < 4; ++j) {
            int n = n0 + j * 16 + lm;
            bfv[j] = *(const short8*)(w1t + (size_t)n * 512 + col);
        }
#pragma unroll
        for (int i = 0; i < 2; ++i)
#pragma unroll
            for (int j = 0; j < 4; ++j)
                acc1[i][j] = __builtin_amdgcn_mfma_f32_16x16x32_bf16(af[i], bfv[j], acc1[i][j], 0, 0, 0);
    }
#pragma unroll
    for (int i = 0; i < 2; ++i)
#pragma unroll
        for (int j = 0; j < 4; ++j)
#pragma unroll
            for (int r = 0; r < 4; ++r) {
                int m = i * 16 + rr + r;
                int n = n0 + j * 16 + lm;
                float v = acc1[i][j][r] + b1[n];
                z1s[m][n] = f2b(gelu_exact(v));
            }
    __syncthreads();

    // L2: [32,256] @ w2t[128][256]^T -> gelu -> z2s [32,128]
    f32x4 acc2[2][2];
#pragma unroll
    for (int i = 0; i < 2; ++i)
#pragma unroll
        for (int j = 0; j < 2; ++j) acc2[i][j] = (f32x4){0.f, 0.f, 0.f, 0.f};
    const int n0b = wave * 32;
#pragma unroll
    for (int ks = 0; ks < 8; ++ks) {
        short8 af[2], bfv[2];
#pragma unroll
        for (int i = 0; i < 2; ++i) af[i] = *(const short8*)&z1s[i * 16 + lm][ks * 32 + lk];
#pragma unroll
        for (int j = 0; j < 2; ++j) {
            int n = n0b + j * 16 + lm;
            bfv[j] = *(const short8*)(w2t + (size_t)n * 256 + ks * 32 + lk);
        }
#pragma unroll
        for (int i = 0; i < 2; ++i)
#pragma unroll
            for (int j = 0; j < 2; ++j)
                acc2[i][j] = __builtin_amdgcn_mfma_f32_16x16x32_bf16(af[i], bfv[j], acc2[i][j], 0, 0, 0);
    }
#pragma unroll
    for (int i = 0; i < 2; ++i)
#pragma unroll
        for (int j = 0; j < 2; ++j)
#pragma unroll
            for (int r = 0; r < 4; ++r) {
                int m = i * 16 + rr + r;
                int n = n0b + j * 16 + lm;
                float v = acc2[i][j][r] + b2[n];
                z2s[m][n] = f2b(gelu_exact(v));
            }
    __syncthreads();

    // L3: [32,128] @ w3[128,2] + b3 (fp32 out)
    if (wave == 0) {
        int e = lane >> 1, c = lane & 1;
        float s = b3[c];
        for (int k = 0; k < 128; ++k) s += b2f(z2s[e][k]) * w3[k * 2 + c];
        int ge = e0 + e;
        if (ge < M) outp[(size_t)ge * 2 + c] = s;
    }
}

// ---------------- launch ----------------
extern "C" void kernel_launch(void* const* d_in, const int* in_sizes, int n_in,
                              void* d_out, int out_size, void* d_ws, size_t ws_size,
                              hipStream_t stream) {
    const float* x          = (const float*)d_in[0];
    const int*   edge_index = (const int*)d_in[1];
    const int*   edge_type  = (const int*)d_in[2];
    const int*   dec_edges  = (const int*)d_in[3];
    const float* W1         = (const float*)d_in[4];
    const float* root1      = (const float*)d_in[5];
    const float* b1         = (const float*)d_in[6];
    const float* W2         = (const float*)d_in[7];
    const float* root2      = (const float*)d_in[8];
    const float* b2         = (const float*)d_in[9];
    const float* ln1_g      = (const float*)d_in[10];
    const float* ln1_b      = (const float*)d_in[11];
    const float* ln2_g      = (const float*)d_in[12];
    const float* ln2_b      = (const float*)d_in[13];
    const float* mlp_w1     = (const float*)d_in[14];
    const float* mlp_b1     = (const float*)d_in[15];
    const float* mlp_w2     = (const float*)d_in[16];
    const float* mlp_b2     = (const float*)d_in[17];
    const float* mlp_w3     = (const float*)d_in[18];
    const float* mlp_b3     = (const float*)d_in[19];

    char* ws = (char*)d_ws;
    size_t off = 0;
    auto alloc = [&](size_t bytes) {
        void* p = ws + off;
        off += (bytes + 255) & ~(size_t)255;
        return p;
    };
    // total ~106 MB
    ushort*       Achunk  = (ushort*)alloc((size_t)CHUNK * K2 * 2);       // 37.7 MB
    ushort*       B1t     = (ushort*)alloc((size_t)HID * K1 * 2);
    ushort*       B2t     = (ushort*)alloc((size_t)HID * K2 * 2);
    ushort*       w1t     = (ushort*)alloc((size_t)256 * 512 * 2);
    ushort*       w2t     = (ushort*)alloc((size_t)128 * 256 * 2);
    ushort*       h1ln    = (ushort*)alloc((size_t)N_NODES * HID * 2);    // 25.6 MB
    ushort*       hfin    = (ushort*)alloc((size_t)N_NODES * HID * 2);    // 25.6 MB
    float*        hrawc   = (float*)alloc((size_t)CHUNK * HID * 4);       // 8.4 MB
    int*          row_ptr = (int*)alloc((size_t)(N_NODES + 1) * 4);
    int*          tmp     = (int*)alloc((size_t)N_NODES * 4);
    unsigned int* epk     = (unsigned int*)alloc((size_t)E_EDGES * 4);    // 6.4 MB

    // CSR build
    hipMemsetAsync(tmp, 0, (size_t)N_NODES * 4, stream);
    count_kernel<<<E_EDGES / 256, 256, 0, stream>>>(edge_index, tmp);
    scan_kernel<<<1, 1024, 0, stream>>>(tmp, row_ptr, N_NODES);
    hipMemsetAsync(tmp, 0, (size_t)N_NODES * 4, stream);
    fill_kernel<<<E_EDGES / 256, 256, 0, stream>>>(edge_index, edge_type, row_ptr, tmp, epk);

    // weight packs
    pack_enc<<<(HID * K1 + HID * K2 + 255) / 256, 256, 0, stream>>>(root1, W1, root2, W2, B1t, B2t);
    pack_mlp<<<(256 * 512 + 128 * 256 + 255) / 256, 256, 0, stream>>>(mlp_w1, mlp_w2, w1t, w2t);

    // conv1
    for (int c = 0; c < NCHUNK; ++c) {
        int n0 = c * CHUNK;
        int m = N_NODES - n0; if (m > CHUNK) m = CHUNK;
        agg1_kernel<<<m, 128, 0, stream>>>(x, row_ptr, epk, Achunk, n0);
        gemm64<<<dim3((m + 63) / 64, 4), 256, 0, stream>>>(Achunk, B1t, hrawc, m, HID, K1);
        ln_kernel<<<(m + 3) / 4, 256, 0, stream>>>(hrawc, b1, ln1_g, ln1_b, nullptr, h1ln, n0, m);
    }

    // conv2
    for (int c = 0; c < NCHUNK; ++c) {
        int n0 = c * CHUNK;
        int m = N_NODES - n0; if (m > CHUNK) m = CHUNK;
        agg2_kernel<<<m, 256, 0, stream>>>(h1ln, row_ptr, epk, Achunk, n0);
        gemm64<<<dim3((m + 63) / 64, 4), 256, 0, stream>>>(Achunk, B2t, hrawc, m, HID, K2);
        ln_kernel<<<(m + 3) / 4, 256, 0, stream>>>(hrawc, b2, ln2_g, ln2_b, h1ln, hfin, n0, m);
    }

    // decode
    decode_kernel<<<M_DEC / 32, 256, 0, stream>>>(hfin, dec_edges, w1t, mlp_b1, w2t, mlp_b2,
                                                  mlp_w3, mlp_b3, (float*)d_out, M_DEC);
}

// Round 6
// 1309.877 us; speedup vs baseline: 2.8818x; 1.3907x over previous
//
#include <hip/hip_runtime.h>
#include <math.h>

typedef __attribute__((ext_vector_type(8))) short short8;
typedef __attribute__((ext_vector_type(4))) float f32x4;

#define N_NODES 50000
#define NUM_REL 8
#define IN_DIM 128
#define HID 256
#define E_EDGES 1600000
#define M_DEC 200000
#define K1 1152
#define K2 2304
#define LN_EPS 1e-5f

__device__ __forceinline__ float b2f(ushort u) {
    union { unsigned int i; float f; } v; v.i = ((unsigned int)u) << 16; return v.f;
}
__device__ __forceinline__ ushort f2b(float f) {
    union { float f; unsigned int i; } v; v.f = f;
    unsigned int r = v.i + 0x7FFFu + ((v.i >> 16) & 1u);
    return (ushort)(r >> 16);
}
__device__ __forceinline__ float gelu_exact(float x) {
    return 0.5f * x * (1.0f + erff(x * 0.70710678118654752f));
}

// ---------------- CSR build ----------------
__global__ void count_kernel(const int* __restrict__ ei, int* __restrict__ cnt) {
    int e = blockIdx.x * 256 + threadIdx.x;
    if (e < E_EDGES) atomicAdd(&cnt[ei[E_EDGES + e]], 1);
}

__global__ void scan_kernel(const int* __restrict__ cnt, int* __restrict__ row_ptr, int n) {
    __shared__ int tsum[1024];
    const int t = threadIdx.x;
    const int CH = (n + 1023) / 1024;
    const int base = t * CH;
    int s = 0;
    for (int i = 0; i < CH; ++i) { int idx = base + i; if (idx < n) s += cnt[idx]; }
    tsum[t] = s;
    __syncthreads();
    for (int off = 1; off < 1024; off <<= 1) {
        int v = (t >= off) ? tsum[t - off] : 0;
        __syncthreads();
        tsum[t] += v;
        __syncthreads();
    }
    int run = tsum[t] - s;
    for (int i = 0; i < CH; ++i) {
        int idx = base + i;
        if (idx < n) { row_ptr[idx] = run; run += cnt[idx]; }
    }
    if (t == 1023) row_ptr[n] = tsum[1023];
}

__global__ void fill_kernel(const int* __restrict__ ei, const int* __restrict__ et,
                            const int* __restrict__ row_ptr, int* __restrict__ cursor,
                            unsigned int* __restrict__ epk) {
    int e = blockIdx.x * 256 + threadIdx.x;
    if (e >= E_EDGES) return;
    int src = ei[e];
    int dst = ei[E_EDGES + e];
    int r   = et[e];
    int pos = row_ptr[dst] + atomicAdd(&cursor[dst], 1);
    if (pos >= 0 && pos < E_EDGES)
        epk[pos] = (unsigned int)src | ((unsigned int)r << 16);
}

// ---------------- weight packing: fp32 -> bf16 transposed Bt[n][k] ----------------
__global__ void pack_enc(const float* __restrict__ root1, const float* __restrict__ W1,
                         const float* __restrict__ root2, const float* __restrict__ W2,
                         ushort* __restrict__ B1t, ushort* __restrict__ B2t) {
    int idx = blockIdx.x * 256 + threadIdx.x;
    const int n1 = HID * K1;
    if (idx < n1) {
        int n = idx / K1, k = idx % K1;
        float v;
        if (k < IN_DIM) v = root1[k * HID + n];
        else { int kk = k - IN_DIM; v = W1[(size_t)(kk >> 7) * IN_DIM * HID + (kk & 127) * HID + n]; }
        B1t[(size_t)n * K1 + k] = f2b(v);
    } else {
        int j = idx - n1;
        if (j >= HID * K2) return;
        int n = j / K2, k = j % K2;
        float v;
        if (k < HID) v = root2[k * HID + n];
        else { int kk = k - HID; v = W2[(size_t)(kk >> 8) * HID * HID + (kk & 255) * HID + n]; }
        B2t[(size_t)n * K2 + k] = f2b(v);
    }
}

// wuvt[512][256]: n<256 -> mlp_w1[k][n] (U = h @ W1_top); n>=256 -> mlp_w1[256+k][n-256] (V)
// w2t[128][256]: mlp_w2[k][n]
__global__ void pack_mlp(const float* __restrict__ mw1, const float* __restrict__ mw2,
                         ushort* __restrict__ wuvt, ushort* __restrict__ w2t) {
    int idx = blockIdx.x * 256 + threadIdx.x;
    const int n1 = 512 * 256;
    if (idx < n1) {
        int n = idx / 256, k = idx % 256;
        float v = (n < 256) ? mw1[(size_t)k * 256 + n] : mw1[(size_t)(256 + k) * 256 + (n - 256)];
        wuvt[(size_t)n * 256 + k] = f2b(v);
    } else {
        int j = idx - n1;
        if (j >= 128 * 256) return;
        int n = j / 256, k = j % 256;
        w2t[n * 256 + k] = f2b(mw2[k * 128 + n]);
    }
}

// ---------------- aggregation (4-way edge-unrolled), chunked ----------------
__global__ void agg1_kernel(const float* __restrict__ x, const int* __restrict__ row_ptr,
                            const unsigned int* __restrict__ epk, ushort* __restrict__ Achunk,
                            int n0) {
    __shared__ float acc[NUM_REL * IN_DIM];
    __shared__ int cnt[NUM_REL];
    const int n = n0 + blockIdx.x, t = threadIdx.x;   // 128 threads
    if (n >= N_NODES) return;
    for (int i = t; i < NUM_REL * IN_DIM; i += 128) acc[i] = 0.f;
    if (t < NUM_REL) cnt[t] = 0;
    __syncthreads();
    int beg = row_ptr[n], end = row_ptr[n + 1];
    if (beg < 0) beg = 0;
    if (end > E_EDGES) end = E_EDGES;
    int e = beg;
    for (; e + 3 < end; e += 4) {
        unsigned int p0 = epk[e], p1 = epk[e+1], p2 = epk[e+2], p3 = epk[e+3];
        float f0 = x[(size_t)(p0 & 0xFFFFu) * IN_DIM + t];
        float f1 = x[(size_t)(p1 & 0xFFFFu) * IN_DIM + t];
        float f2 = x[(size_t)(p2 & 0xFFFFu) * IN_DIM + t];
        float f3 = x[(size_t)(p3 & 0xFFFFu) * IN_DIM + t];
        acc[((p0 >> 16) & 7u) * IN_DIM + t] += f0;
        acc[((p1 >> 16) & 7u) * IN_DIM + t] += f1;
        acc[((p2 >> 16) & 7u) * IN_DIM + t] += f2;
        acc[((p3 >> 16) & 7u) * IN_DIM + t] += f3;
        if (t == 0) { cnt[(p0>>16)&7u]++; cnt[(p1>>16)&7u]++; cnt[(p2>>16)&7u]++; cnt[(p3>>16)&7u]++; }
    }
    for (; e < end; ++e) {
        unsigned int p = epk[e];
        acc[((p >> 16) & 7u) * IN_DIM + t] += x[(size_t)(p & 0xFFFFu) * IN_DIM + t];
        if (t == 0) cnt[(p>>16)&7u]++;
    }
    __syncthreads();
    ushort* Arow = Achunk + (size_t)blockIdx.x * K1;
    Arow[t] = f2b(x[(size_t)n * IN_DIM + t]);
#pragma unroll
    for (int r = 0; r < NUM_REL; ++r) {
        float c = (float)cnt[r];
        float inv = c > 0.f ? 1.f / c : 0.f;
        Arow[IN_DIM + r * IN_DIM + t] = f2b(acc[r * IN_DIM + t] * inv);
    }
}

__global__ void agg2_kernel(const ushort* __restrict__ h1, const int* __restrict__ row_ptr,
                            const unsigned int* __restrict__ epk, ushort* __restrict__ Achunk,
                            int n0) {
    __shared__ float acc[NUM_REL * HID];
    __shared__ int cnt[NUM_REL];
    const int n = n0 + blockIdx.x, t = threadIdx.x;   // 256 threads
    if (n >= N_NODES) return;
    for (int i = t; i < NUM_REL * HID; i += 256) acc[i] = 0.f;
    if (t < NUM_REL) cnt[t] = 0;
    __syncthreads();
    int beg = row_ptr[n], end = row_ptr[n + 1];
    if (beg < 0) beg = 0;
    if (end > E_EDGES) end = E_EDGES;
    int e = beg;
    for (; e + 3 < end; e += 4) {
        unsigned int p0 = epk[e], p1 = epk[e+1], p2 = epk[e+2], p3 = epk[e+3];
        float f0 = b2f(h1[(size_t)(p0 & 0xFFFFu) * HID + t]);
        float f1 = b2f(h1[(size_t)(p1 & 0xFFFFu) * HID + t]);
        float f2 = b2f(h1[(size_t)(p2 & 0xFFFFu) * HID + t]);
        float f3 = b2f(h1[(size_t)(p3 & 0xFFFFu) * HID + t]);
        acc[((p0 >> 16) & 7u) * HID + t] += f0;
        acc[((p1 >> 16) & 7u) * HID + t] += f1;
        acc[((p2 >> 16) & 7u) * HID + t] += f2;
        acc[((p3 >> 16) & 7u) * HID + t] += f3;
        if (t == 0) { cnt[(p0>>16)&7u]++; cnt[(p1>>16)&7u]++; cnt[(p2>>16)&7u]++; cnt[(p3>>16)&7u]++; }
    }
    for (; e < end; ++e) {
        unsigned int p = epk[e];
        acc[((p >> 16) & 7u) * HID + t] += b2f(h1[(size_t)(p & 0xFFFFu) * HID + t]);
        if (t == 0) cnt[(p>>16)&7u]++;
    }
    __syncthreads();
    ushort* Arow = Achunk + (size_t)blockIdx.x * K2;
    Arow[t] = h1[(size_t)n * HID + t];
#pragma unroll
    for (int r = 0; r < NUM_REL; ++r) {
        float c = (float)cnt[r];
        float inv = c > 0.f ? 1.f / c : 0.f;
        Arow[HID + r * HID + t] = f2b(acc[r * HID + t] * inv);
    }
}

// ---------------- GEMM 64x256 tile + fused bias/ReLU/LN(/residual) epilogue ----------------
// g==nullptr -> plain bf16 store (used for U|V). Waves split 256 cols; A staged once.
__global__ __launch_bounds__(256) void gemm_fused(
    const ushort* __restrict__ A, const ushort* __restrict__ Bt,
    int lda, int M, int K,
    const float* __restrict__ bias, const float* __restrict__ g,
    const float* __restrict__ bvec, const ushort* __restrict__ resid,
    ushort* __restrict__ outp, int ldc, int rowOff) {
    __shared__ __align__(16) ushort As[64][72];
    __shared__ __align__(16) ushort Bs[256][72];
    __shared__ float partS[64][4];
    __shared__ float partQ[64][4];
    __shared__ float muS[64], rsS[64];
    const int tid = threadIdx.x;
    const int wave = tid >> 6, lane = tid & 63;
    const int cc = lane & 15, qd = lane >> 4;
    const int lk = qd * 8;
    const int row0 = blockIdx.x * 64;
    const int colBase = blockIdx.y * 256;
    const int wn = wave * 64;
    f32x4 acc[4][4];
#pragma unroll
    for (int i = 0; i < 4; ++i)
#pragma unroll
        for (int j = 0; j < 4; ++j) acc[i][j] = (f32x4){0.f, 0.f, 0.f, 0.f};

    for (int k0 = 0; k0 < K; k0 += 64) {
#pragma unroll
        for (int i = 0; i < 2; ++i) {
            int c = tid + i * 256;
            int r = c >> 3, kc = (c & 7) * 8;
            uint4 va = make_uint4(0u, 0u, 0u, 0u);
            int gr = row0 + r;
            if (gr < M) va = *(const uint4*)(A + (size_t)gr * lda + k0 + kc);
            *(uint4*)&As[r][kc] = va;
        }
#pragma unroll
        for (int i = 0; i < 8; ++i) {
            int c = tid + i * 256;
            int r = c >> 3, kc = (c & 7) * 8;
            *(uint4*)&Bs[r][kc] = *(const uint4*)(Bt + (size_t)(colBase + r) * K + k0 + kc);
        }
        __syncthreads();
#pragma unroll
        for (int kk = 0; kk < 2; ++kk) {
            short8 af[4], bfv[4];
#pragma unroll
            for (int i = 0; i < 4; ++i) af[i] = *(const short8*)&As[i * 16 + cc][kk * 32 + lk];
#pragma unroll
            for (int j = 0; j < 4; ++j) bfv[j] = *(const short8*)&Bs[wn + j * 16 + cc][kk * 32 + lk];
#pragma unroll
            for (int i = 0; i < 4; ++i)
#pragma unroll
                for (int j = 0; j < 4; ++j)
                    acc[i][j] = __builtin_amdgcn_mfma_f32_16x16x32_bf16(af[i], bfv[j], acc[i][j], 0, 0, 0);
        }
        __syncthreads();
    }

    if (g) {
        // bias + relu in place
#pragma unroll
        for (int j = 0; j < 4; ++j) {
            float bcol = bias[wn + j * 16 + cc];
#pragma unroll
            for (int i = 0; i < 4; ++i)
#pragma unroll
                for (int r = 0; r < 4; ++r)
                    acc[i][j][r] = fmaxf(acc[i][j][r] + bcol, 0.f);
        }
        // per-row partial sums over this wave's 64 cols
#pragma unroll
        for (int i = 0; i < 4; ++i)
#pragma unroll
            for (int r = 0; r < 4; ++r) {
                float s = acc[i][0][r] + acc[i][1][r] + acc[i][2][r] + acc[i][3][r];
                float q = acc[i][0][r] * acc[i][0][r] + acc[i][1][r] * acc[i][1][r]
                        + acc[i][2][r] * acc[i][2][r] + acc[i][3][r] * acc[i][3][r];
#pragma unroll
                for (int off = 1; off <= 8; off <<= 1) {
                    s += __shfl_xor(s, off, 64);
                    q += __shfl_xor(q, off, 64);
                }
                if (cc == 0) {
                    int row = i * 16 + qd * 4 + r;
                    partS[row][wave] = s;
                    partQ[row][wave] = q;
                }
            }
        __syncthreads();
        if (tid < 64) {
            float S = partS[tid][0] + partS[tid][1] + partS[tid][2] + partS[tid][3];
            float Q = partQ[tid][0] + partQ[tid][1] + partQ[tid][2] + partQ[tid][3];
            float mu = S * (1.f / 256.f);
            float var = Q * (1.f / 256.f) - mu * mu;
            muS[tid] = mu;
            rsS[tid] = rsqrtf(fmaxf(var, 0.f) + LN_EPS);
        }
        __syncthreads();
#pragma unroll
        for (int i = 0; i < 4; ++i)
#pragma unroll
            for (int r = 0; r < 4; ++r) {
                int row = i * 16 + qd * 4 + r;
                int grow = row0 + row;
                if (grow >= M) continue;
                float mu = muS[row], rs = rsS[row];
                size_t base = (size_t)(rowOff + grow) * ldc;
#pragma unroll
                for (int j = 0; j < 4; ++j) {
                    int col = wn + j * 16 + cc;
                    float val = (acc[i][j][r] - mu) * rs * g[col] + bvec[col];
                    if (resid) val += b2f(resid[base + col]);
                    outp[base + col] = f2b(val);
                }
            }
    } else {
#pragma unroll
        for (int i = 0; i < 4; ++i)
#pragma unroll
            for (int r = 0; r < 4; ++r) {
                int grow = row0 + i * 16 + qd * 4 + r;
                if (grow >= M) continue;
                size_t base = (size_t)(rowOff + grow) * ldc;
#pragma unroll
                for (int j = 0; j < 4; ++j) {
                    int col = colBase + wn + j * 16 + cc;
                    outp[base + col] = f2b(acc[i][j][r]);
                }
            }
    }
}

// ---------------- edge decode: z1 = gelu(U[a]+V[b]+b1); z2 = gelu(z1@w2); out = z2@w3+b3 ----
__global__ __launch_bounds__(256) void edge_kernel(
    const ushort* __restrict__ uv, const int* __restrict__ dec,
    const float* __restrict__ b1, const ushort* __restrict__ w2t,
    const float* __restrict__ b2, const float* __restrict__ w3,
    const float* __restrict__ b3, float* __restrict__ outp, int M) {
    __shared__ __align__(16) ushort z1s[64][264];
    __shared__ __align__(16) ushort z2s[64][136];
    __shared__ float b1s[256], b2s[128], w3s[256];
    const int tid = threadIdx.x;
    const int wave = tid >> 6, lane = tid & 63;
    const int cc = lane & 15, qd = lane >> 4, lk = qd * 8, rr = qd * 4;
    const int e0 = blockIdx.x * 64;

    b1s[tid] = b1[tid];
    if (tid < 128) b2s[tid] = b2[tid];
    w3s[tid] = w3[tid];
    __syncthreads();

    // stage1: z1 = gelu(U[a] + V[b] + b1), 4 threads per edge
    {
        int e = tid >> 2, seg = tid & 3;
        int ge = e0 + e;
        int a = dec[(size_t)ge * 2];
        int b = dec[(size_t)ge * 2 + 1];
        if (a < 0) a = 0; if (a >= N_NODES) a = N_NODES - 1;
        if (b < 0) b = 0; if (b >= N_NODES) b = N_NODES - 1;
        const ushort* up = uv + (size_t)a * 512;
        const ushort* vp = uv + (size_t)b * 512 + 256;
        int d0 = seg * 64;
#pragma unroll
        for (int c8 = 0; c8 < 8; ++c8) {
            int d = d0 + c8 * 8;
            short8 us = *(const short8*)(up + d);
            short8 vs = *(const short8*)(vp + d);
            short8 zs;
#pragma unroll
            for (int l = 0; l < 8; ++l) {
                float z = b2f((ushort)us[l]) + b2f((ushort)vs[l]) + b1s[d + l];
                zs[l] = (short)f2b(gelu_exact(z));
            }
            *(short8*)&z1s[e][d] = zs;
        }
    }
    __syncthreads();

    // stage2: [64,256] @ w2t[128][256]^T -> gelu -> z2s [64,128]
    f32x4 acc[4][2];
#pragma unroll
    for (int i = 0; i < 4; ++i)
#pragma unroll
        for (int j = 0; j < 2; ++j) acc[i][j] = (f32x4){0.f, 0.f, 0.f, 0.f};
    const int n0 = wave * 32;
#pragma unroll
    for (int ks = 0; ks < 8; ++ks) {
        short8 af[4], bfv[2];
#pragma unroll
        for (int i = 0; i < 4; ++i) af[i] = *(const short8*)&z1s[i * 16 + cc][ks * 32 + lk];
#pragma unroll
        for (int j = 0; j < 2; ++j)
            bfv[j] = *(const short8*)(w2t + (size_t)(n0 + j * 16 + cc) * 256 + ks * 32 + lk);
#pragma unroll
        for (int i = 0; i < 4; ++i)
#pragma unroll
            for (int j = 0; j < 2; ++j)
                acc[i][j] = __builtin_amdgcn_mfma_f32_16x16x32_bf16(af[i], bfv[j], acc[i][j], 0, 0, 0);
    }
#pragma unroll
    for (int i = 0; i < 4; ++i)
#pragma unroll
        for (int j = 0; j < 2; ++j)
#pragma unroll
            for (int r = 0; r < 4; ++r) {
                int m = i * 16 + rr + r;
                int n = n0 + j * 16 + cc;
                z2s[m][n] = f2b(gelu_exact(acc[i][j][r] + b2s[n]));
            }
    __syncthreads();

    // stage3: [64,128] @ w3[128,2] + b3
    if (tid < 128) {
        int e = tid >> 1, c = tid & 1;
        float s = b3[c];
        for (int k = 0; k < 128; ++k) s += b2f(z2s[e][k]) * w3s[k * 2 + c];
        int ge = e0 + e;
        if (ge < M) outp[(size_t)ge * 2 + c] = s;
    }
}

// ---------------- launch ----------------
extern "C" void kernel_launch(void* const* d_in, const int* in_sizes, int n_in,
                              void* d_out, int out_size, void* d_ws, size_t ws_size,
                              hipStream_t stream) {
    const float* x          = (const float*)d_in[0];
    const int*   edge_index = (const int*)d_in[1];
    const int*   edge_type  = (const int*)d_in[2];
    const int*   dec_edges  = (const int*)d_in[3];
    const float* W1         = (const float*)d_in[4];
    const float* root1      = (const float*)d_in[5];
    const float* b1         = (const float*)d_in[6];
    const float* W2         = (const float*)d_in[7];
    const float* root2      = (const float*)d_in[8];
    const float* b2         = (const float*)d_in[9];
    const float* ln1_g      = (const float*)d_in[10];
    const float* ln1_b      = (const float*)d_in[11];
    const float* ln2_g      = (const float*)d_in[12];
    const float* ln2_b      = (const float*)d_in[13];
    const float* mlp_w1     = (const float*)d_in[14];
    const float* mlp_b1     = (const float*)d_in[15];
    const float* mlp_w2     = (const float*)d_in[16];
    const float* mlp_b2     = (const float*)d_in[17];
    const float* mlp_w3     = (const float*)d_in[18];
    const float* mlp_b3     = (const float*)d_in[19];

    char* ws = (char*)d_ws;
    size_t off = 0;
    auto alloc = [&](size_t bytes) {
        void* p = ws + off;
        off += (bytes + 255) & ~(size_t)255;
        return p;
    };
    unsigned int* epk     = (unsigned int*)alloc((size_t)E_EDGES * 4);      // 6.4 MB
    int*          row_ptr = (int*)alloc((size_t)(N_NODES + 1) * 4);
    int*          tmp     = (int*)alloc((size_t)N_NODES * 4);
    ushort*       B1t     = (ushort*)alloc((size_t)HID * K1 * 2);           // 0.59 MB
    ushort*       B2t     = (ushort*)alloc((size_t)HID * K2 * 2);           // 1.18 MB
    ushort*       wuvt    = (ushort*)alloc((size_t)512 * 256 * 2);          // 0.26 MB
    ushort*       w2t     = (ushort*)alloc((size_t)128 * 256 * 2);          // 0.07 MB
    ushort*       hfin    = (ushort*)alloc((size_t)N_NODES * HID * 2);      // 25.6 MB

    // region: [h1ln | Achunk], later aliased by uv (uv only needed after both are dead)
    size_t regionOff = off;
    ushort* h1ln  = (ushort*)(ws + regionOff);
    ushort* uvbuf = h1ln;                                                   // alias
    size_t h1b = (((size_t)N_NODES * HID * 2) + 255) & ~(size_t)255;        // 25.6 MB
    ushort* Achunk = (ushort*)(ws + regionOff + h1b);
    long long chunkB = (long long)ws_size - (long long)(regionOff + h1b);
    int chunk = 64;
    if (chunkB > 0) {
        long long c = chunkB / ((long long)K2 * 2);
        if (c > N_NODES) c = N_NODES;
        c &= ~63LL;
        if (c >= 64) chunk = (int)c;
    }

    // CSR build
    hipMemsetAsync(tmp, 0, (size_t)N_NODES * 4, stream);
    count_kernel<<<(E_EDGES + 255) / 256, 256, 0, stream>>>(edge_index, tmp);
    scan_kernel<<<1, 1024, 0, stream>>>(tmp, row_ptr, N_NODES);
    hipMemsetAsync(tmp, 0, (size_t)N_NODES * 4, stream);
    fill_kernel<<<(E_EDGES + 255) / 256, 256, 0, stream>>>(edge_index, edge_type, row_ptr, tmp, epk);

    // weight packs
    pack_enc<<<(HID * K1 + HID * K2 + 255) / 256, 256, 0, stream>>>(root1, W1, root2, W2, B1t, B2t);
    pack_mlp<<<(512 * 256 + 128 * 256 + 255) / 256, 256, 0, stream>>>(mlp_w1, mlp_w2, wuvt, w2t);

    // conv1: agg -> GEMM(+bias,relu,LN) per chunk
    for (int n0 = 0; n0 < N_NODES; n0 += chunk) {
        int m = N_NODES - n0; if (m > chunk) m = chunk;
        agg1_kernel<<<m, 128, 0, stream>>>(x, row_ptr, epk, Achunk, n0);
        gemm_fused<<<dim3((m + 63) / 64, 1), 256, 0, stream>>>(
            Achunk, B1t, K1, m, K1, b1, ln1_g, ln1_b, nullptr, h1ln, HID, n0);
    }
    // conv2: agg -> GEMM(+bias,relu,LN,+h1 residual) per chunk
    for (int n0 = 0; n0 < N_NODES; n0 += chunk) {
        int m = N_NODES - n0; if (m > chunk) m = chunk;
        agg2_kernel<<<m, 256, 0, stream>>>(h1ln, row_ptr, epk, Achunk, n0);
        gemm_fused<<<dim3((m + 63) / 64, 1), 256, 0, stream>>>(
            Achunk, B2t, K2, m, K2, b2, ln2_g, ln2_b, h1ln, hfin, HID, n0);
    }

    // U|V = hfin @ [W1_top | W1_bot]  ([50000, 512] bf16, plain epilogue)
    gemm_fused<<<dim3((N_NODES + 63) / 64, 2), 256, 0, stream>>>(
        hfin, wuvt, HID, N_NODES, HID, nullptr, nullptr, nullptr, nullptr, uvbuf, 512, 0);

    // edge decode
    edge_kernel<<<(M_DEC + 63) / 64, 256, 0, stream>>>(
        uvbuf, dec_edges, mlp_b1, w2t, mlp_b2, mlp_w3, mlp_b3, (float*)d_out, M_DEC);
}